// Round 11
// baseline (466.892 us; speedup 1.0000x reference)
//
#include <hip/hip_runtime.h>

#define NN 50000
#define NE 800000
#define FIN 128
#define H 64
#define NG 64
#define BN_EPS 1e-5f
#define INV_N (1.0f / 50000.0f)
#define NB_SCAN 196  // ceil(NN/256)

// ---------------- degree histogram (int) ----------------
__global__ void deg_count(const int* __restrict__ dst, int* __restrict__ deg, int E) {
    int e = blockIdx.x * blockDim.x + threadIdx.x;
    if (e < E) atomicAdd(&deg[dst[e]], 1);
}

// ---------------- setup: dinv, zero accumulators, transpose all W ----------------
__global__ void setup_misc(const int* __restrict__ deg, float* __restrict__ dinv,
                           const float* __restrict__ W0, const float* __restrict__ W1,
                           const float* __restrict__ W2, float* __restrict__ Wt0,
                           float* __restrict__ Wt1, float* __restrict__ Wt2,
                           float* __restrict__ z0, float* __restrict__ z1,
                           float* __restrict__ z2, float* __restrict__ poolcnt, int n) {
    int i = blockIdx.x * 256 + threadIdx.x;
    if (i < n) dinv[i] = rsqrtf((float)deg[i] + 1.0f);
    if (i < 128) { z0[i] = 0.f; z1[i] = 0.f; z2[i] = 0.f; }
    if (i < NG * H + NG) poolcnt[i] = 0.f;
    if (i < FIN * 64) {
        int k = i >> 6, o = i & 63;
        Wt0[i] = W0[o * FIN + k];
    }
    if (i < H * 64) {
        int k = i >> 6, o = i & 63;
        Wt1[i] = W1[o * H + k];
        Wt2[i] = W2[o * H + k];
    }
}

// ---------------- prefix sum (exclusive) over deg -> row_start ----------------
__global__ void scan_block(const int* __restrict__ deg, int* __restrict__ row_start,
                           int* __restrict__ aux, int n) {
    __shared__ int s[256];
    int i = blockIdx.x * 256 + threadIdx.x;
    int v = (i < n) ? deg[i] : 0;
    s[threadIdx.x] = v;
    __syncthreads();
    for (int off = 1; off < 256; off <<= 1) {
        int t = (threadIdx.x >= off) ? s[threadIdx.x - off] : 0;
        __syncthreads();
        s[threadIdx.x] += t;
        __syncthreads();
    }
    if (i < n) row_start[i] = s[threadIdx.x] - v;  // exclusive
    if (threadIdx.x == 255) aux[blockIdx.x] = s[255];
}

__global__ void scan_aux(int* __restrict__ aux, int nb) {
    __shared__ int s[256];
    int v = (threadIdx.x < nb) ? aux[threadIdx.x] : 0;
    s[threadIdx.x] = v;
    __syncthreads();
    for (int off = 1; off < 256; off <<= 1) {
        int t = (threadIdx.x >= off) ? s[threadIdx.x - off] : 0;
        __syncthreads();
        s[threadIdx.x] += t;
        __syncthreads();
    }
    if (threadIdx.x < nb) aux[threadIdx.x] = s[threadIdx.x] - v;  // exclusive
}

__global__ void scan_fixup(int* __restrict__ row_start, const int* __restrict__ aux,
                           int* __restrict__ cursor, int n, int E) {
    int i = blockIdx.x * 256 + threadIdx.x;
    if (i < n) {
        int rs = row_start[i] + aux[i >> 8];
        row_start[i] = rs;
        cursor[i] = rs;
    }
    if (i == 0) row_start[n] = E;
}

// ---------------- scatter edges into CSR (by dst) ----------------
// R10 post-mortem: plain random 4B stores writeback a full 64B line EACH
// (WRITE_SIZE 52.3 MB = 800k x 64B exactly; zero L2 write-combining).
// Atomics execute in L2 and write back only on eviction (deg_count evidence),
// so the scatter store is issued as atomicExch.
__global__ void csr_scatter(const int* __restrict__ src, const int* __restrict__ dst,
                            int* __restrict__ cursor, int* __restrict__ csr_src, int E) {
    int e = blockIdx.x * blockDim.x + threadIdx.x;
    if (e >= E) return;
    int d = dst[e];
    int j = atomicAdd(&cursor[d], 1);
    atomicExch(&csr_src[j], src[e]);
}

// ---------------- tiled matmul: out = relu_bn(x) @ W^T ----------------
template <int K>
__global__ __launch_bounds__(256, 4) void matmul_tile(const float* __restrict__ x,
                                                      const float* __restrict__ Wtg,
                                                      const float* __restrict__ st,
                                                      const float* __restrict__ gamma,
                                                      const float* __restrict__ beta,
                                                      float* __restrict__ out, int n) {
    __shared__ float Xs[64 * 68];
    __shared__ float Ws[64 * 64];
    const int base = blockIdx.x * 64;
    const int q = threadIdx.x >> 4;         // 0..15
    const int co = (threadIdx.x & 15) * 4;  // 0..60

    float4 a0 = make_float4(0.f, 0.f, 0.f, 0.f);
    float4 a1 = a0, a2 = a0, a3 = a0;

    for (int kc = 0; kc < K; kc += 64) {
        if (kc) __syncthreads();
        for (int i = threadIdx.x; i < 64 * 64; i += 256) Ws[i] = Wtg[kc * 64 + i];
        {
            const int kq = (threadIdx.x & 15) * 4;
            float4 sc = make_float4(1.f, 1.f, 1.f, 1.f);
            float4 sh = make_float4(0.f, 0.f, 0.f, 0.f);
            if (st) {
                int kk = kc + kq;
                float4 s = *(const float4*)&st[kk];
                float4 ss = *(const float4*)&st[64 + kk];
                float4 gm = *(const float4*)&gamma[kk];
                float4 bt = *(const float4*)&beta[kk];
                float mx = s.x * INV_N, my = s.y * INV_N, mz = s.z * INV_N, mw = s.w * INV_N;
                sc.x = gm.x * rsqrtf(ss.x * INV_N - mx * mx + BN_EPS);
                sc.y = gm.y * rsqrtf(ss.y * INV_N - my * my + BN_EPS);
                sc.z = gm.z * rsqrtf(ss.z * INV_N - mz * mz + BN_EPS);
                sc.w = gm.w * rsqrtf(ss.w * INV_N - mw * mw + BN_EPS);
                sh.x = bt.x - mx * sc.x;
                sh.y = bt.y - my * sc.y;
                sh.z = bt.z - mz * sc.z;
                sh.w = bt.w - mw * sc.w;
            }
            for (int j = 0; j < 4; ++j) {
                int r = (threadIdx.x >> 4) + j * 16;
                int row = base + r;
                float4 v = make_float4(0.f, 0.f, 0.f, 0.f);
                if (row < n) v = *(const float4*)&x[(size_t)row * K + kc + kq];
                if (st) {
                    v.x = fmaxf(v.x * sc.x + sh.x, 0.f);
                    v.y = fmaxf(v.y * sc.y + sh.y, 0.f);
                    v.z = fmaxf(v.z * sc.z + sh.z, 0.f);
                    v.w = fmaxf(v.w * sc.w + sh.w, 0.f);
                }
                *(float4*)&Xs[r * 68 + kq] = v;
            }
        }
        __syncthreads();

#pragma unroll 2
        for (int k = 0; k < 64; k += 4) {
            float4 x0 = *(const float4*)&Xs[(q + 0) * 68 + k];
            float4 x1 = *(const float4*)&Xs[(q + 16) * 68 + k];
            float4 x2 = *(const float4*)&Xs[(q + 32) * 68 + k];
            float4 x3 = *(const float4*)&Xs[(q + 48) * 68 + k];
            float4 w0 = *(const float4*)&Ws[(k + 0) * 64 + co];
            float4 w1 = *(const float4*)&Ws[(k + 1) * 64 + co];
            float4 w2 = *(const float4*)&Ws[(k + 2) * 64 + co];
            float4 w3 = *(const float4*)&Ws[(k + 3) * 64 + co];

            a0.x += x0.x * w0.x + x0.y * w1.x + x0.z * w2.x + x0.w * w3.x;
            a0.y += x0.x * w0.y + x0.y * w1.y + x0.z * w2.y + x0.w * w3.y;
            a0.z += x0.x * w0.z + x0.y * w1.z + x0.z * w2.z + x0.w * w3.z;
            a0.w += x0.x * w0.w + x0.y * w1.w + x0.z * w2.w + x0.w * w3.w;

            a1.x += x1.x * w0.x + x1.y * w1.x + x1.z * w2.x + x1.w * w3.x;
            a1.y += x1.x * w0.y + x1.y * w1.y + x1.z * w2.y + x1.w * w3.y;
            a1.z += x1.x * w0.z + x1.y * w1.z + x1.z * w2.z + x1.w * w3.z;
            a1.w += x1.x * w0.w + x1.y * w1.w + x1.z * w2.w + x1.w * w3.w;

            a2.x += x2.x * w0.x + x2.y * w1.x + x2.z * w2.x + x2.w * w3.x;
            a2.y += x2.x * w0.y + x2.y * w1.y + x2.z * w2.y + x2.w * w3.y;
            a2.z += x2.x * w0.z + x2.y * w1.z + x2.z * w2.z + x2.w * w3.z;
            a2.w += x2.x * w0.w + x2.y * w1.w + x2.z * w2.w + x2.w * w3.w;

            a3.x += x3.x * w0.x + x3.y * w1.x + x3.z * w2.x + x3.w * w3.x;
            a3.y += x3.x * w0.y + x3.y * w1.y + x3.z * w2.y + x3.w * w3.y;
            a3.z += x3.x * w0.z + x3.y * w1.z + x3.z * w2.z + x3.w * w3.z;
            a3.w += x3.x * w0.w + x3.y * w1.w + x3.z * w2.w + x3.w * w3.w;
        }
    }

    int r0 = base + q;
    if (r0 < n) *(float4*)&out[(size_t)r0 * H + co] = a0;
    if (r0 + 16 < n) *(float4*)&out[(size_t)(r0 + 16) * H + co] = a1;
    if (r0 + 32 < n) *(float4*)&out[(size_t)(r0 + 32) * H + co] = a2;
    if (r0 + 48 < n) *(float4*)&out[(size_t)(r0 + 48) * H + co] = a3;
}

// ---------------- fused GCN aggregation: gather over CSR + self-loop + bias -------------
__global__ void gcn_gather(const float* __restrict__ h, const int* __restrict__ row_start,
                           const int* __restrict__ csr_src, const float* __restrict__ dinv,
                           const float* __restrict__ bias, float* __restrict__ out, int n) {
    int d = blockIdx.x * 4 + (threadIdx.x >> 6);
    int c = threadIdx.x & 63;
    if (d >= n) return;
    float di = dinv[d];
    float base = h[(size_t)d * H + c] * di * di + bias[c];
    float a0 = 0.f, a1 = 0.f, a2 = 0.f, a3 = 0.f, a4 = 0.f, a5 = 0.f, a6 = 0.f, a7 = 0.f;
    int j0 = row_start[d], j1 = row_start[d + 1];
    int j = j0;
    for (; j + 8 <= j1; j += 8) {
        int s0 = csr_src[j + 0], s1 = csr_src[j + 1], s2 = csr_src[j + 2], s3 = csr_src[j + 3];
        int s4 = csr_src[j + 4], s5 = csr_src[j + 5], s6 = csr_src[j + 6], s7 = csr_src[j + 7];
        float w0 = dinv[s0], w1 = dinv[s1], w2 = dinv[s2], w3 = dinv[s3];
        float w4 = dinv[s4], w5 = dinv[s5], w6 = dinv[s6], w7 = dinv[s7];
        a0 += h[(size_t)s0 * H + c] * w0;
        a1 += h[(size_t)s1 * H + c] * w1;
        a2 += h[(size_t)s2 * H + c] * w2;
        a3 += h[(size_t)s3 * H + c] * w3;
        a4 += h[(size_t)s4 * H + c] * w4;
        a5 += h[(size_t)s5 * H + c] * w5;
        a6 += h[(size_t)s6 * H + c] * w6;
        a7 += h[(size_t)s7 * H + c] * w7;
    }
    for (; j + 4 <= j1; j += 4) {
        int s0 = csr_src[j + 0], s1 = csr_src[j + 1], s2 = csr_src[j + 2], s3 = csr_src[j + 3];
        float w0 = dinv[s0], w1 = dinv[s1], w2 = dinv[s2], w3 = dinv[s3];
        a0 += h[(size_t)s0 * H + c] * w0;
        a1 += h[(size_t)s1 * H + c] * w1;
        a2 += h[(size_t)s2 * H + c] * w2;
        a3 += h[(size_t)s3 * H + c] * w3;
    }
    for (; j < j1; ++j) {
        int s = csr_src[j];
        a0 += h[(size_t)s * H + c] * dinv[s];
    }
    out[(size_t)d * H + c] = base + di * (((a0 + a1) + (a2 + a3)) + ((a4 + a5) + (a6 + a7)));
}

// ---------------- batchnorm stats ----------------
// R10: grid widened 196->782 blocks (64 rows/block) — same strided shape but 4x
// the waves; the 196-block version was latency-bound like R9's pool_seg.
__global__ void bn_stats(const float* __restrict__ x, float* __restrict__ sum,
                         float* __restrict__ sumsq, int n) {
    int c = threadIdx.x & 63;
    int rg = threadIdx.x >> 6;  // 0..3
    int base = blockIdx.x * 64;
    float s0 = 0.f, q0 = 0.f, s1 = 0.f, q1 = 0.f, s2 = 0.f, q2 = 0.f, s3 = 0.f, q3 = 0.f;
    for (int r = rg; r < 64; r += 16) {
        int r0 = base + r, r1 = base + r + 4, r2 = base + r + 8, r3 = base + r + 12;
        if (r0 < n) { float v = x[(size_t)r0 * H + c]; s0 += v; q0 += v * v; }
        if (r1 < n) { float v = x[(size_t)r1 * H + c]; s1 += v; q1 += v * v; }
        if (r2 < n) { float v = x[(size_t)r2 * H + c]; s2 += v; q2 += v * v; }
        if (r3 < n) { float v = x[(size_t)r3 * H + c]; s3 += v; q3 += v * v; }
    }
    float s = (s0 + s1) + (s2 + s3);
    float sq = (q0 + q1) + (q2 + q3);
    __shared__ float ls[256], lq[256];
    ls[threadIdx.x] = s;
    lq[threadIdx.x] = sq;
    __syncthreads();
    if (rg == 0) {
        s = ls[c] + ls[c + 64] + ls[c + 128] + ls[c + 192];
        sq = lq[c] + lq[c + 64] + lq[c + 128] + lq[c + 192];
        atomicAdd(&sum[c], s);
        atomicAdd(&sumsq[c], sq);
    }
}

// ---------------- global mean pool (fuses last BN finalize+apply+ReLU) ----------------
#define PROWS 16
__global__ void pool_seg(const float* __restrict__ h, const float* __restrict__ st,
                         const float* __restrict__ gamma, const float* __restrict__ beta,
                         const int* __restrict__ batch, float* __restrict__ pool,
                         float* __restrict__ cnt, int n) {
    int wave = blockIdx.x * 4 + (threadIdx.x >> 6);
    int c = threadIdx.x & 63;
    int r0 = wave * PROWS;
    if (r0 >= n) return;
    int r1 = min(r0 + PROWS, n);
    float mean = st[c] * INV_N;
    float var = st[64 + c] * INV_N - mean * mean;
    float sc = gamma[c] * rsqrtf(var + BN_EPS);
    float sh = beta[c] - mean * sc;
    int cur = batch[r0];
    float acc = 0.f;
    int nlocal = 0;
    for (int r = r0; r < r1; ++r) {
        int g = batch[r];
        if (g != cur) {
            atomicAdd(&pool[cur * H + c], acc);
            if (c == 0) atomicAdd(&cnt[cur], (float)nlocal);
            cur = g;
            acc = 0.f;
            nlocal = 0;
        }
        acc += fmaxf(h[(size_t)r * H + c] * sc + sh, 0.f);
        ++nlocal;
    }
    atomicAdd(&pool[cur * H + c], acc);
    if (c == 0) atomicAdd(&cnt[cur], (float)nlocal);
}

// ---------------- final MLP: lane = (graph, j) pair; shuffle-reduce over j --------------
__global__ void final_mlp(const float* __restrict__ pool, const float* __restrict__ cnt,
                          const float* __restrict__ l1w, const float* __restrict__ l1b,
                          const float* __restrict__ l2w, const float* __restrict__ l2b,
                          float* __restrict__ out) {
    int tid = blockIdx.x * 256 + threadIdx.x;
    int g = tid >> 5;
    int j = tid & 31;
    if (g >= NG) return;
    float inv = 1.0f / fmaxf(cnt[g], 1.0f);
    float s = l1b[j];
    for (int k = 0; k < H; ++k) s += pool[g * H + k] * inv * l1w[j * H + k];
    float v = fmaxf(s, 0.0f) * l2w[j];
    for (int off = 16; off > 0; off >>= 1) v += __shfl_down(v, off, 32);
    if (j == 0) out[g] = v + l2b[0];
}

extern "C" void kernel_launch(void* const* d_in, const int* in_sizes, int n_in,
                              void* d_out, int out_size, void* d_ws, size_t ws_size,
                              hipStream_t stream) {
    const float* x = (const float*)d_in[0];
    const int* ei = (const int*)d_in[1];
    const int* batch = (const int*)d_in[2];
    const float* W[3] = {(const float*)d_in[3], (const float*)d_in[7], (const float*)d_in[11]};
    const float* b[3] = {(const float*)d_in[4], (const float*)d_in[8], (const float*)d_in[12]};
    const float* g[3] = {(const float*)d_in[5], (const float*)d_in[9], (const float*)d_in[13]};
    const float* be[3] = {(const float*)d_in[6], (const float*)d_in[10], (const float*)d_in[14]};
    const float* l1w = (const float*)d_in[15];
    const float* l1b = (const float*)d_in[16];
    const float* l2w = (const float*)d_in[17];
    const float* l2b = (const float*)d_in[18];
    float* out = (float*)d_out;

    const int* src = ei;
    const int* dst = ei + NE;

    // ---- workspace layout (4-byte units) ----
    char* wsb = (char*)d_ws;
    size_t off = 0;
    auto alloc = [&](size_t elems) {
        void* p = wsb + off;
        off += elems * 4;
        return p;
    };
    float* dinv = (float*)alloc(50048);
    float* bufA = (float*)alloc((size_t)NN * H);
    float* bufB = (float*)alloc((size_t)NN * H);
    float* st[3] = {(float*)alloc(256), (float*)alloc(256), (float*)alloc(256)};
    float* pool = (float*)alloc(NG * H);
    float* cnt = (float*)alloc(64);
    float* Wt[3] = {(float*)alloc(FIN * 64), (float*)alloc(H * 64), (float*)alloc(H * 64)};
    int* deg = (int*)alloc(50048);
    int* row_start = (int*)alloc(50112);  // NN+1
    int* aux = (int*)alloc(256);
    int* cursor = (int*)alloc(50048);
    int* csr_src = (int*)alloc(NE);

    // ---- build dinv + CSR (by dst) + transposed weights ----
    hipMemsetAsync(deg, 0, NN * sizeof(int), stream);
    deg_count<<<(NE + 255) / 256, 256, 0, stream>>>(dst, deg, NE);
    setup_misc<<<NB_SCAN, 256, 0, stream>>>(deg, dinv, W[0], W[1], W[2], Wt[0], Wt[1], Wt[2],
                                            st[0], st[1], st[2], pool, NN);
    scan_block<<<NB_SCAN, 256, 0, stream>>>(deg, row_start, aux, NN);
    scan_aux<<<1, 256, 0, stream>>>(aux, NB_SCAN);
    scan_fixup<<<NB_SCAN, 256, 0, stream>>>(row_start, aux, cursor, NN, NE);
    csr_scatter<<<(NE + 255) / 256, 256, 0, stream>>>(src, dst, cursor, csr_src, NE);

    const int grid_mm = (NN + 63) / 64;   // 782
    const int grid_rows = (NN + 3) / 4;   // 12500

    // ---- 3 GCN layers (BN of layer L-1 fused into layer L's X staging) ----
    for (int L = 0; L < 3; ++L) {
        if (L == 0)
            matmul_tile<FIN><<<grid_mm, 256, 0, stream>>>(x, Wt[0], nullptr, nullptr, nullptr,
                                                          bufA, NN);
        else
            matmul_tile<H><<<grid_mm, 256, 0, stream>>>(bufB, Wt[L], st[L - 1], g[L - 1],
                                                        be[L - 1], bufA, NN);
        gcn_gather<<<grid_rows, 256, 0, stream>>>(bufA, row_start, csr_src, dinv, b[L], bufB, NN);
        bn_stats<<<grid_mm, 256, 0, stream>>>(bufB, st[L], st[L] + 64, NN);
    }

    // ---- global mean pool (fused BN of layer 2) + MLP head ----
    const int pool_waves = (NN + PROWS - 1) / PROWS;  // 3125
    pool_seg<<<(pool_waves + 3) / 4, 256, 0, stream>>>(bufB, st[2], g[2], be[2], batch, pool,
                                                       cnt, NN);
    final_mlp<<<8, 256, 0, stream>>>(pool, cnt, l1w, l1b, l2w, l2b, out);
}

// Round 12
// 422.924 us; speedup vs baseline: 1.1040x; 1.1040x over previous
//
#include <hip/hip_runtime.h>

#define NN 50000
#define NE 800000
#define FIN 128
#define H 64
#define NG 64
#define BN_EPS 1e-5f
#define INV_N (1.0f / 50000.0f)
#define NB_SCAN 196  // ceil(NN/256)
#define NBKT 196     // dst buckets of 256 nodes

// ---------------- degree histogram (int) ----------------
__global__ void deg_count(const int* __restrict__ dst, int* __restrict__ deg, int E) {
    int e = blockIdx.x * blockDim.x + threadIdx.x;
    if (e < E) atomicAdd(&deg[dst[e]], 1);
}

// ---------------- setup: dinv, zero accumulators, transpose all W ----------------
__global__ void setup_misc(const int* __restrict__ deg, float* __restrict__ dinv,
                           const float* __restrict__ W0, const float* __restrict__ W1,
                           const float* __restrict__ W2, float* __restrict__ Wt0,
                           float* __restrict__ Wt1, float* __restrict__ Wt2,
                           float* __restrict__ z0, float* __restrict__ z1,
                           float* __restrict__ z2, float* __restrict__ poolcnt, int n) {
    int i = blockIdx.x * 256 + threadIdx.x;
    if (i < n) dinv[i] = rsqrtf((float)deg[i] + 1.0f);
    if (i < 128) { z0[i] = 0.f; z1[i] = 0.f; z2[i] = 0.f; }
    if (i < NG * H + NG) poolcnt[i] = 0.f;
    if (i < FIN * 64) {
        int k = i >> 6, o = i & 63;
        Wt0[i] = W0[o * FIN + k];
    }
    if (i < H * 64) {
        int k = i >> 6, o = i & 63;
        Wt1[i] = W1[o * H + k];
        Wt2[i] = W2[o * H + k];
    }
}

// ---------------- prefix sum (exclusive) over deg -> row_start ----------------
__global__ void scan_block(const int* __restrict__ deg, int* __restrict__ row_start,
                           int* __restrict__ aux, int n) {
    __shared__ int s[256];
    int i = blockIdx.x * 256 + threadIdx.x;
    int v = (i < n) ? deg[i] : 0;
    s[threadIdx.x] = v;
    __syncthreads();
    for (int off = 1; off < 256; off <<= 1) {
        int t = (threadIdx.x >= off) ? s[threadIdx.x - off] : 0;
        __syncthreads();
        s[threadIdx.x] += t;
        __syncthreads();
    }
    if (i < n) row_start[i] = s[threadIdx.x] - v;  // exclusive
    if (threadIdx.x == 255) aux[blockIdx.x] = s[255];
}

__global__ void scan_aux(int* __restrict__ aux, int nb) {
    __shared__ int s[256];
    int v = (threadIdx.x < nb) ? aux[threadIdx.x] : 0;
    s[threadIdx.x] = v;
    __syncthreads();
    for (int off = 1; off < 256; off <<= 1) {
        int t = (threadIdx.x >= off) ? s[threadIdx.x - off] : 0;
        __syncthreads();
        s[threadIdx.x] += t;
        __syncthreads();
    }
    if (threadIdx.x < nb) aux[threadIdx.x] = s[threadIdx.x] - v;  // exclusive
}

// also extracts bucket bases/cursors (row_start at 256-node boundaries)
__global__ void scan_fixup(int* __restrict__ row_start, const int* __restrict__ aux,
                           int* __restrict__ bb, int* __restrict__ bcur, int n, int E) {
    int i = blockIdx.x * 256 + threadIdx.x;
    if (i < n) {
        int rs = row_start[i] + aux[i >> 8];
        row_start[i] = rs;
        if ((i & 255) == 0) { bb[i >> 8] = rs; bcur[i >> 8] = rs; }
    }
    if (i == 0) { row_start[n] = E; bb[NBKT] = E; }
}

// ---------------- CSR build, two-pass binned (R11 post-mortem) ----------------
// R10/R11: single-pass random 4B scatter wrote back a full 64B line per store
// (WRITE_SIZE 50-52 MB for a 3.2 MB payload); atomicExch did NOT help (R11:
// same 50 MB, slower). Fix locality instead: bin by dst>>8 with LDS counts and
// bucket-contiguous staged writes (pass A), then per-bucket scatter whose
// random writes span only ~16 KB (pass B) -> lines written back once.
__global__ void bin_edges(const int* __restrict__ src, const int* __restrict__ dst,
                          int* __restrict__ bcur, unsigned int* __restrict__ staged, int E) {
    __shared__ int cnt[NBKT];
    __shared__ int offs[NBKT];
    const int chunk = (E + gridDim.x - 1) / gridDim.x;
    const int e0 = blockIdx.x * chunk;
    const int e1 = min(e0 + chunk, E);
    for (int i = threadIdx.x; i < NBKT; i += 256) cnt[i] = 0;
    __syncthreads();
    for (int e = e0 + threadIdx.x; e < e1; e += 256) atomicAdd(&cnt[dst[e] >> 8], 1);
    __syncthreads();
    for (int i = threadIdx.x; i < NBKT; i += 256) {
        int c = cnt[i];
        offs[i] = c ? atomicAdd(&bcur[i], c) : 0;
        cnt[i] = 0;
    }
    __syncthreads();
    for (int e = e0 + threadIdx.x; e < e1; e += 256) {
        int d = dst[e];
        int bkt = d >> 8;
        int idx = atomicAdd(&cnt[bkt], 1);
        // src < 50000 fits in 16 bits; dst low byte in bits 16..23
        staged[offs[bkt] + idx] = (unsigned int)src[e] | ((unsigned int)(d & 255) << 16);
    }
}

__global__ void csr_build(const unsigned int* __restrict__ staged,
                          const int* __restrict__ row_start, const int* __restrict__ bb,
                          int* __restrict__ csr_src, int n) {
    __shared__ int cur[256];
    int b = blockIdx.x;
    int node = b * 256 + threadIdx.x;
    cur[threadIdx.x] = (node < n) ? row_start[node] : 0;
    __syncthreads();
    int e0 = bb[b], e1 = bb[b + 1];
    for (int e = e0 + threadIdx.x; e < e1; e += 256) {
        unsigned int u = staged[e];
        int j = atomicAdd(&cur[(u >> 16) & 255], 1);
        csr_src[j] = (int)(u & 0xFFFFu);
    }
}

// ---------------- tiled matmul: out = relu_bn(x) @ W^T ----------------
template <int K>
__global__ __launch_bounds__(256, 4) void matmul_tile(const float* __restrict__ x,
                                                      const float* __restrict__ Wtg,
                                                      const float* __restrict__ st,
                                                      const float* __restrict__ gamma,
                                                      const float* __restrict__ beta,
                                                      float* __restrict__ out, int n) {
    __shared__ float Xs[64 * 68];
    __shared__ float Ws[64 * 64];
    const int base = blockIdx.x * 64;
    const int q = threadIdx.x >> 4;         // 0..15
    const int co = (threadIdx.x & 15) * 4;  // 0..60

    float4 a0 = make_float4(0.f, 0.f, 0.f, 0.f);
    float4 a1 = a0, a2 = a0, a3 = a0;

    for (int kc = 0; kc < K; kc += 64) {
        if (kc) __syncthreads();
        for (int i = threadIdx.x; i < 64 * 64; i += 256) Ws[i] = Wtg[kc * 64 + i];
        {
            const int kq = (threadIdx.x & 15) * 4;
            float4 sc = make_float4(1.f, 1.f, 1.f, 1.f);
            float4 sh = make_float4(0.f, 0.f, 0.f, 0.f);
            if (st) {
                int kk = kc + kq;
                float4 s = *(const float4*)&st[kk];
                float4 ss = *(const float4*)&st[64 + kk];
                float4 gm = *(const float4*)&gamma[kk];
                float4 bt = *(const float4*)&beta[kk];
                float mx = s.x * INV_N, my = s.y * INV_N, mz = s.z * INV_N, mw = s.w * INV_N;
                sc.x = gm.x * rsqrtf(ss.x * INV_N - mx * mx + BN_EPS);
                sc.y = gm.y * rsqrtf(ss.y * INV_N - my * my + BN_EPS);
                sc.z = gm.z * rsqrtf(ss.z * INV_N - mz * mz + BN_EPS);
                sc.w = gm.w * rsqrtf(ss.w * INV_N - mw * mw + BN_EPS);
                sh.x = bt.x - mx * sc.x;
                sh.y = bt.y - my * sc.y;
                sh.z = bt.z - mz * sc.z;
                sh.w = bt.w - mw * sc.w;
            }
            for (int j = 0; j < 4; ++j) {
                int r = (threadIdx.x >> 4) + j * 16;
                int row = base + r;
                float4 v = make_float4(0.f, 0.f, 0.f, 0.f);
                if (row < n) v = *(const float4*)&x[(size_t)row * K + kc + kq];
                if (st) {
                    v.x = fmaxf(v.x * sc.x + sh.x, 0.f);
                    v.y = fmaxf(v.y * sc.y + sh.y, 0.f);
                    v.z = fmaxf(v.z * sc.z + sh.z, 0.f);
                    v.w = fmaxf(v.w * sc.w + sh.w, 0.f);
                }
                *(float4*)&Xs[r * 68 + kq] = v;
            }
        }
        __syncthreads();

#pragma unroll 2
        for (int k = 0; k < 64; k += 4) {
            float4 x0 = *(const float4*)&Xs[(q + 0) * 68 + k];
            float4 x1 = *(const float4*)&Xs[(q + 16) * 68 + k];
            float4 x2 = *(const float4*)&Xs[(q + 32) * 68 + k];
            float4 x3 = *(const float4*)&Xs[(q + 48) * 68 + k];
            float4 w0 = *(const float4*)&Ws[(k + 0) * 64 + co];
            float4 w1 = *(const float4*)&Ws[(k + 1) * 64 + co];
            float4 w2 = *(const float4*)&Ws[(k + 2) * 64 + co];
            float4 w3 = *(const float4*)&Ws[(k + 3) * 64 + co];

            a0.x += x0.x * w0.x + x0.y * w1.x + x0.z * w2.x + x0.w * w3.x;
            a0.y += x0.x * w0.y + x0.y * w1.y + x0.z * w2.y + x0.w * w3.y;
            a0.z += x0.x * w0.z + x0.y * w1.z + x0.z * w2.z + x0.w * w3.z;
            a0.w += x0.x * w0.w + x0.y * w1.w + x0.z * w2.w + x0.w * w3.w;

            a1.x += x1.x * w0.x + x1.y * w1.x + x1.z * w2.x + x1.w * w3.x;
            a1.y += x1.x * w0.y + x1.y * w1.y + x1.z * w2.y + x1.w * w3.y;
            a1.z += x1.x * w0.z + x1.y * w1.z + x1.z * w2.z + x1.w * w3.z;
            a1.w += x1.x * w0.w + x1.y * w1.w + x1.z * w2.w + x1.w * w3.w;

            a2.x += x2.x * w0.x + x2.y * w1.x + x2.z * w2.x + x2.w * w3.x;
            a2.y += x2.x * w0.y + x2.y * w1.y + x2.z * w2.y + x2.w * w3.y;
            a2.z += x2.x * w0.z + x2.y * w1.z + x2.z * w2.z + x2.w * w3.z;
            a2.w += x2.x * w0.w + x2.y * w1.w + x2.z * w2.w + x2.w * w3.w;

            a3.x += x3.x * w0.x + x3.y * w1.x + x3.z * w2.x + x3.w * w3.x;
            a3.y += x3.x * w0.y + x3.y * w1.y + x3.z * w2.y + x3.w * w3.y;
            a3.z += x3.x * w0.z + x3.y * w1.z + x3.z * w2.z + x3.w * w3.z;
            a3.w += x3.x * w0.w + x3.y * w1.w + x3.z * w2.w + x3.w * w3.w;
        }
    }

    int r0 = base + q;
    if (r0 < n) *(float4*)&out[(size_t)r0 * H + co] = a0;
    if (r0 + 16 < n) *(float4*)&out[(size_t)(r0 + 16) * H + co] = a1;
    if (r0 + 32 < n) *(float4*)&out[(size_t)(r0 + 32) * H + co] = a2;
    if (r0 + 48 < n) *(float4*)&out[(size_t)(r0 + 48) * H + co] = a3;
}

// ---------------- fused GCN aggregation: gather over CSR + self-loop + bias -------------
__global__ void gcn_gather(const float* __restrict__ h, const int* __restrict__ row_start,
                           const int* __restrict__ csr_src, const float* __restrict__ dinv,
                           const float* __restrict__ bias, float* __restrict__ out, int n) {
    int d = blockIdx.x * 4 + (threadIdx.x >> 6);
    int c = threadIdx.x & 63;
    if (d >= n) return;
    float di = dinv[d];
    float base = h[(size_t)d * H + c] * di * di + bias[c];
    float a0 = 0.f, a1 = 0.f, a2 = 0.f, a3 = 0.f, a4 = 0.f, a5 = 0.f, a6 = 0.f, a7 = 0.f;
    int j0 = row_start[d], j1 = row_start[d + 1];
    int j = j0;
    for (; j + 8 <= j1; j += 8) {
        int s0 = csr_src[j + 0], s1 = csr_src[j + 1], s2 = csr_src[j + 2], s3 = csr_src[j + 3];
        int s4 = csr_src[j + 4], s5 = csr_src[j + 5], s6 = csr_src[j + 6], s7 = csr_src[j + 7];
        float w0 = dinv[s0], w1 = dinv[s1], w2 = dinv[s2], w3 = dinv[s3];
        float w4 = dinv[s4], w5 = dinv[s5], w6 = dinv[s6], w7 = dinv[s7];
        a0 += h[(size_t)s0 * H + c] * w0;
        a1 += h[(size_t)s1 * H + c] * w1;
        a2 += h[(size_t)s2 * H + c] * w2;
        a3 += h[(size_t)s3 * H + c] * w3;
        a4 += h[(size_t)s4 * H + c] * w4;
        a5 += h[(size_t)s5 * H + c] * w5;
        a6 += h[(size_t)s6 * H + c] * w6;
        a7 += h[(size_t)s7 * H + c] * w7;
    }
    for (; j + 4 <= j1; j += 4) {
        int s0 = csr_src[j + 0], s1 = csr_src[j + 1], s2 = csr_src[j + 2], s3 = csr_src[j + 3];
        float w0 = dinv[s0], w1 = dinv[s1], w2 = dinv[s2], w3 = dinv[s3];
        a0 += h[(size_t)s0 * H + c] * w0;
        a1 += h[(size_t)s1 * H + c] * w1;
        a2 += h[(size_t)s2 * H + c] * w2;
        a3 += h[(size_t)s3 * H + c] * w3;
    }
    for (; j < j1; ++j) {
        int s = csr_src[j];
        a0 += h[(size_t)s * H + c] * dinv[s];
    }
    out[(size_t)d * H + c] = base + di * (((a0 + a1) + (a2 + a3)) + ((a4 + a5) + (a6 + a7)));
}

// ---------------- batchnorm stats ----------------
__global__ void bn_stats(const float* __restrict__ x, float* __restrict__ sum,
                         float* __restrict__ sumsq, int n) {
    int c = threadIdx.x & 63;
    int rg = threadIdx.x >> 6;  // 0..3
    int base = blockIdx.x * 64;
    float s0 = 0.f, q0 = 0.f, s1 = 0.f, q1 = 0.f, s2 = 0.f, q2 = 0.f, s3 = 0.f, q3 = 0.f;
    for (int r = rg; r < 64; r += 16) {
        int r0 = base + r, r1 = base + r + 4, r2 = base + r + 8, r3 = base + r + 12;
        if (r0 < n) { float v = x[(size_t)r0 * H + c]; s0 += v; q0 += v * v; }
        if (r1 < n) { float v = x[(size_t)r1 * H + c]; s1 += v; q1 += v * v; }
        if (r2 < n) { float v = x[(size_t)r2 * H + c]; s2 += v; q2 += v * v; }
        if (r3 < n) { float v = x[(size_t)r3 * H + c]; s3 += v; q3 += v * v; }
    }
    float s = (s0 + s1) + (s2 + s3);
    float sq = (q0 + q1) + (q2 + q3);
    __shared__ float ls[256], lq[256];
    ls[threadIdx.x] = s;
    lq[threadIdx.x] = sq;
    __syncthreads();
    if (rg == 0) {
        s = ls[c] + ls[c + 64] + ls[c + 128] + ls[c + 192];
        sq = lq[c] + lq[c + 64] + lq[c + 128] + lq[c + 192];
        atomicAdd(&sum[c], s);
        atomicAdd(&sumsq[c], sq);
    }
}

// ---------------- global mean pool (fuses last BN finalize+apply+ReLU) ----------------
#define PROWS 16
__global__ void pool_seg(const float* __restrict__ h, const float* __restrict__ st,
                         const float* __restrict__ gamma, const float* __restrict__ beta,
                         const int* __restrict__ batch, float* __restrict__ pool,
                         float* __restrict__ cnt, int n) {
    int wave = blockIdx.x * 4 + (threadIdx.x >> 6);
    int c = threadIdx.x & 63;
    int r0 = wave * PROWS;
    if (r0 >= n) return;
    int r1 = min(r0 + PROWS, n);
    float mean = st[c] * INV_N;
    float var = st[64 + c] * INV_N - mean * mean;
    float sc = gamma[c] * rsqrtf(var + BN_EPS);
    float sh = beta[c] - mean * sc;
    int cur = batch[r0];
    float acc = 0.f;
    int nlocal = 0;
    for (int r = r0; r < r1; ++r) {
        int g = batch[r];
        if (g != cur) {
            atomicAdd(&pool[cur * H + c], acc);
            if (c == 0) atomicAdd(&cnt[cur], (float)nlocal);
            cur = g;
            acc = 0.f;
            nlocal = 0;
        }
        acc += fmaxf(h[(size_t)r * H + c] * sc + sh, 0.f);
        ++nlocal;
    }
    atomicAdd(&pool[cur * H + c], acc);
    if (c == 0) atomicAdd(&cnt[cur], (float)nlocal);
}

// ---------------- final MLP: lane = (graph, j) pair; shuffle-reduce over j --------------
__global__ void final_mlp(const float* __restrict__ pool, const float* __restrict__ cnt,
                          const float* __restrict__ l1w, const float* __restrict__ l1b,
                          const float* __restrict__ l2w, const float* __restrict__ l2b,
                          float* __restrict__ out) {
    int tid = blockIdx.x * 256 + threadIdx.x;
    int g = tid >> 5;
    int j = tid & 31;
    if (g >= NG) return;
    float inv = 1.0f / fmaxf(cnt[g], 1.0f);
    float s = l1b[j];
    for (int k = 0; k < H; ++k) s += pool[g * H + k] * inv * l1w[j * H + k];
    float v = fmaxf(s, 0.0f) * l2w[j];
    for (int off = 16; off > 0; off >>= 1) v += __shfl_down(v, off, 32);
    if (j == 0) out[g] = v + l2b[0];
}

extern "C" void kernel_launch(void* const* d_in, const int* in_sizes, int n_in,
                              void* d_out, int out_size, void* d_ws, size_t ws_size,
                              hipStream_t stream) {
    const float* x = (const float*)d_in[0];
    const int* ei = (const int*)d_in[1];
    const int* batch = (const int*)d_in[2];
    const float* W[3] = {(const float*)d_in[3], (const float*)d_in[7], (const float*)d_in[11]};
    const float* b[3] = {(const float*)d_in[4], (const float*)d_in[8], (const float*)d_in[12]};
    const float* g[3] = {(const float*)d_in[5], (const float*)d_in[9], (const float*)d_in[13]};
    const float* be[3] = {(const float*)d_in[6], (const float*)d_in[10], (const float*)d_in[14]};
    const float* l1w = (const float*)d_in[15];
    const float* l1b = (const float*)d_in[16];
    const float* l2w = (const float*)d_in[17];
    const float* l2b = (const float*)d_in[18];
    float* out = (float*)d_out;

    const int* src = ei;
    const int* dst = ei + NE;

    // ---- workspace layout (4-byte units) ----
    char* wsb = (char*)d_ws;
    size_t off = 0;
    auto alloc = [&](size_t elems) {
        void* p = wsb + off;
        off += elems * 4;
        return p;
    };
    float* dinv = (float*)alloc(50048);
    float* bufA = (float*)alloc((size_t)NN * H);
    float* bufB = (float*)alloc((size_t)NN * H);
    float* st[3] = {(float*)alloc(256), (float*)alloc(256), (float*)alloc(256)};
    float* pool = (float*)alloc(NG * H);
    float* cnt = (float*)alloc(64);
    float* Wt[3] = {(float*)alloc(FIN * 64), (float*)alloc(H * 64), (float*)alloc(H * 64)};
    int* deg = (int*)alloc(50048);
    int* row_start = (int*)alloc(50112);   // NN+1
    int* aux = (int*)alloc(256);
    int* bb = (int*)alloc(256);            // bucket bases (NBKT+1)
    int* bcur = (int*)alloc(256);          // bucket cursors
    unsigned int* staged = (unsigned int*)alloc(NE);
    int* csr_src = (int*)alloc(NE);

    // ---- build dinv + binned CSR (by dst) + transposed weights ----
    hipMemsetAsync(deg, 0, NN * sizeof(int), stream);
    deg_count<<<(NE + 255) / 256, 256, 0, stream>>>(dst, deg, NE);
    setup_misc<<<NB_SCAN, 256, 0, stream>>>(deg, dinv, W[0], W[1], W[2], Wt[0], Wt[1], Wt[2],
                                            st[0], st[1], st[2], pool, NN);
    scan_block<<<NB_SCAN, 256, 0, stream>>>(deg, row_start, aux, NN);
    scan_aux<<<1, 256, 0, stream>>>(aux, NB_SCAN);
    scan_fixup<<<NB_SCAN, 256, 0, stream>>>(row_start, aux, bb, bcur, NN, NE);
    bin_edges<<<256, 256, 0, stream>>>(src, dst, bcur, staged, NE);
    csr_build<<<NBKT, 256, 0, stream>>>(staged, row_start, bb, csr_src, NN);

    const int grid_mm = (NN + 63) / 64;   // 782
    const int grid_rows = (NN + 3) / 4;   // 12500

    // ---- 3 GCN layers (BN of layer L-1 fused into layer L's X staging) ----
    for (int L = 0; L < 3; ++L) {
        if (L == 0)
            matmul_tile<FIN><<<grid_mm, 256, 0, stream>>>(x, Wt[0], nullptr, nullptr, nullptr,
                                                          bufA, NN);
        else
            matmul_tile<H><<<grid_mm, 256, 0, stream>>>(bufB, Wt[L], st[L - 1], g[L - 1],
                                                        be[L - 1], bufA, NN);
        gcn_gather<<<grid_rows, 256, 0, stream>>>(bufA, row_start, csr_src, dinv, b[L], bufB, NN);
        bn_stats<<<grid_mm, 256, 0, stream>>>(bufB, st[L], st[L] + 64, NN);
    }

    // ---- global mean pool (fused BN of layer 2) + MLP head ----
    const int pool_waves = (NN + PROWS - 1) / PROWS;  // 3125
    pool_seg<<<(pool_waves + 3) / 4, 256, 0, stream>>>(bufB, st[2], g[2], be[2], batch, pool,
                                                       cnt, NN);
    final_mlp<<<8, 256, 0, stream>>>(pool, cnt, l1w, l1b, l2w, l2b, out);
}

// Round 13
// 377.727 us; speedup vs baseline: 1.2361x; 1.1197x over previous
//
#include <hip/hip_runtime.h>

#define NN 50000
#define NE 800000
#define FIN 128
#define H 64
#define NG 64
#define BN_EPS 1e-5f
#define INV_N (1.0f / 50000.0f)
#define NB_SCAN 196  // ceil(NN/256)
#define NBKT 196     // dst buckets of 256 nodes

// ---------------- degree histogram (int) ----------------
__global__ void deg_count(const int* __restrict__ dst, int* __restrict__ deg, int E) {
    int e = blockIdx.x * blockDim.x + threadIdx.x;
    if (e < E) atomicAdd(&deg[dst[e]], 1);
}

// ---------------- setup: dinv, zero accumulator slots, transpose all W ----------------
__global__ void setup_misc(const int* __restrict__ deg, float* __restrict__ dinv,
                           const float* __restrict__ W0, const float* __restrict__ W1,
                           const float* __restrict__ W2, float* __restrict__ Wt0,
                           float* __restrict__ Wt1, float* __restrict__ Wt2,
                           float* __restrict__ sl0, float* __restrict__ sl1,
                           float* __restrict__ sl2, float* __restrict__ poolcnt, int n) {
    int i = blockIdx.x * 256 + threadIdx.x;
    if (i < n) dinv[i] = rsqrtf((float)deg[i] + 1.0f);
    if (i < 64 * 128) { sl0[i] = 0.f; sl1[i] = 0.f; sl2[i] = 0.f; }
    if (i < NG * H + NG) poolcnt[i] = 0.f;
    if (i < FIN * 64) {
        int k = i >> 6, o = i & 63;
        Wt0[i] = W0[o * FIN + k];
    }
    if (i < H * 64) {
        int k = i >> 6, o = i & 63;
        Wt1[i] = W1[o * H + k];
        Wt2[i] = W2[o * H + k];
    }
}

// ---------------- prefix sum (exclusive) over deg -> row_start ----------------
__global__ void scan_block(const int* __restrict__ deg, int* __restrict__ row_start,
                           int* __restrict__ aux, int n) {
    __shared__ int s[256];
    int i = blockIdx.x * 256 + threadIdx.x;
    int v = (i < n) ? deg[i] : 0;
    s[threadIdx.x] = v;
    __syncthreads();
    for (int off = 1; off < 256; off <<= 1) {
        int t = (threadIdx.x >= off) ? s[threadIdx.x - off] : 0;
        __syncthreads();
        s[threadIdx.x] += t;
        __syncthreads();
    }
    if (i < n) row_start[i] = s[threadIdx.x] - v;  // exclusive
    if (threadIdx.x == 255) aux[blockIdx.x] = s[255];
}

__global__ void scan_aux(int* __restrict__ aux, int nb) {
    __shared__ int s[256];
    int v = (threadIdx.x < nb) ? aux[threadIdx.x] : 0;
    s[threadIdx.x] = v;
    __syncthreads();
    for (int off = 1; off < 256; off <<= 1) {
        int t = (threadIdx.x >= off) ? s[threadIdx.x - off] : 0;
        __syncthreads();
        s[threadIdx.x] += t;
        __syncthreads();
    }
    if (threadIdx.x < nb) aux[threadIdx.x] = s[threadIdx.x] - v;  // exclusive
}

// also extracts bucket bases/cursors (row_start at 256-node boundaries)
__global__ void scan_fixup(int* __restrict__ row_start, const int* __restrict__ aux,
                           int* __restrict__ bb, int* __restrict__ bcur, int n, int E) {
    int i = blockIdx.x * 256 + threadIdx.x;
    if (i < n) {
        int rs = row_start[i] + aux[i >> 8];
        row_start[i] = rs;
        if ((i & 255) == 0) { bb[i >> 8] = rs; bcur[i >> 8] = rs; }
    }
    if (i == 0) { row_start[n] = E; bb[NBKT] = E; }
}

// ---------------- CSR build, two-pass binned (see R11 post-mortem) ----------------
__global__ void bin_edges(const int* __restrict__ src, const int* __restrict__ dst,
                          int* __restrict__ bcur, unsigned int* __restrict__ staged, int E) {
    __shared__ int cnt[NBKT];
    __shared__ int offs[NBKT];
    const int chunk = (E + gridDim.x - 1) / gridDim.x;
    const int e0 = blockIdx.x * chunk;
    const int e1 = min(e0 + chunk, E);
    for (int i = threadIdx.x; i < NBKT; i += 256) cnt[i] = 0;
    __syncthreads();
    for (int e = e0 + threadIdx.x; e < e1; e += 256) atomicAdd(&cnt[dst[e] >> 8], 1);
    __syncthreads();
    for (int i = threadIdx.x; i < NBKT; i += 256) {
        int c = cnt[i];
        offs[i] = c ? atomicAdd(&bcur[i], c) : 0;
        cnt[i] = 0;
    }
    __syncthreads();
    for (int e = e0 + threadIdx.x; e < e1; e += 256) {
        int d = dst[e];
        int bkt = d >> 8;
        int idx = atomicAdd(&cnt[bkt], 1);
        staged[offs[bkt] + idx] = (unsigned int)src[e] | ((unsigned int)(d & 255) << 16);
    }
}

__global__ void csr_build(const unsigned int* __restrict__ staged,
                          const int* __restrict__ row_start, const int* __restrict__ bb,
                          int* __restrict__ csr_src, int n) {
    __shared__ int cur[256];
    int b = blockIdx.x;
    int node = b * 256 + threadIdx.x;
    cur[threadIdx.x] = (node < n) ? row_start[node] : 0;
    __syncthreads();
    int e0 = bb[b], e1 = bb[b + 1];
    for (int e = e0 + threadIdx.x; e < e1; e += 256) {
        unsigned int u = staged[e];
        int j = atomicAdd(&cur[(u >> 16) & 255], 1);
        csr_src[j] = (int)(u & 0xFFFFu);
    }
}

// ---------------- tiled matmul: out = relu_bn(x) @ W^T ----------------
template <int K>
__global__ __launch_bounds__(256, 4) void matmul_tile(const float* __restrict__ x,
                                                      const float* __restrict__ Wtg,
                                                      const float* __restrict__ st,
                                                      const float* __restrict__ gamma,
                                                      const float* __restrict__ beta,
                                                      float* __restrict__ out, int n) {
    __shared__ float Xs[64 * 68];
    __shared__ float Ws[64 * 64];
    const int base = blockIdx.x * 64;
    const int q = threadIdx.x >> 4;         // 0..15
    const int co = (threadIdx.x & 15) * 4;  // 0..60

    float4 a0 = make_float4(0.f, 0.f, 0.f, 0.f);
    float4 a1 = a0, a2 = a0, a3 = a0;

    for (int kc = 0; kc < K; kc += 64) {
        if (kc) __syncthreads();
        for (int i = threadIdx.x; i < 64 * 64; i += 256) Ws[i] = Wtg[kc * 64 + i];
        {
            const int kq = (threadIdx.x & 15) * 4;
            float4 sc = make_float4(1.f, 1.f, 1.f, 1.f);
            float4 sh = make_float4(0.f, 0.f, 0.f, 0.f);
            if (st) {
                int kk = kc + kq;
                float4 s = *(const float4*)&st[kk];
                float4 ss = *(const float4*)&st[64 + kk];
                float4 gm = *(const float4*)&gamma[kk];
                float4 bt = *(const float4*)&beta[kk];
                float mx = s.x * INV_N, my = s.y * INV_N, mz = s.z * INV_N, mw = s.w * INV_N;
                sc.x = gm.x * rsqrtf(ss.x * INV_N - mx * mx + BN_EPS);
                sc.y = gm.y * rsqrtf(ss.y * INV_N - my * my + BN_EPS);
                sc.z = gm.z * rsqrtf(ss.z * INV_N - mz * mz + BN_EPS);
                sc.w = gm.w * rsqrtf(ss.w * INV_N - mw * mw + BN_EPS);
                sh.x = bt.x - mx * sc.x;
                sh.y = bt.y - my * sc.y;
                sh.z = bt.z - mz * sc.z;
                sh.w = bt.w - mw * sc.w;
            }
            for (int j = 0; j < 4; ++j) {
                int r = (threadIdx.x >> 4) + j * 16;
                int row = base + r;
                float4 v = make_float4(0.f, 0.f, 0.f, 0.f);
                if (row < n) v = *(const float4*)&x[(size_t)row * K + kc + kq];
                if (st) {
                    v.x = fmaxf(v.x * sc.x + sh.x, 0.f);
                    v.y = fmaxf(v.y * sc.y + sh.y, 0.f);
                    v.z = fmaxf(v.z * sc.z + sh.z, 0.f);
                    v.w = fmaxf(v.w * sc.w + sh.w, 0.f);
                }
                *(float4*)&Xs[r * 68 + kq] = v;
            }
        }
        __syncthreads();

#pragma unroll 2
        for (int k = 0; k < 64; k += 4) {
            float4 x0 = *(const float4*)&Xs[(q + 0) * 68 + k];
            float4 x1 = *(const float4*)&Xs[(q + 16) * 68 + k];
            float4 x2 = *(const float4*)&Xs[(q + 32) * 68 + k];
            float4 x3 = *(const float4*)&Xs[(q + 48) * 68 + k];
            float4 w0 = *(const float4*)&Ws[(k + 0) * 64 + co];
            float4 w1 = *(const float4*)&Ws[(k + 1) * 64 + co];
            float4 w2 = *(const float4*)&Ws[(k + 2) * 64 + co];
            float4 w3 = *(const float4*)&Ws[(k + 3) * 64 + co];

            a0.x += x0.x * w0.x + x0.y * w1.x + x0.z * w2.x + x0.w * w3.x;
            a0.y += x0.x * w0.y + x0.y * w1.y + x0.z * w2.y + x0.w * w3.y;
            a0.z += x0.x * w0.z + x0.y * w1.z + x0.z * w2.z + x0.w * w3.z;
            a0.w += x0.x * w0.w + x0.y * w1.w + x0.z * w2.w + x0.w * w3.w;

            a1.x += x1.x * w0.x + x1.y * w1.x + x1.z * w2.x + x1.w * w3.x;
            a1.y += x1.x * w0.y + x1.y * w1.y + x1.z * w2.y + x1.w * w3.y;
            a1.z += x1.x * w0.z + x1.y * w1.z + x1.z * w2.z + x1.w * w3.z;
            a1.w += x1.x * w0.w + x1.y * w1.w + x1.z * w2.w + x1.w * w3.w;

            a2.x += x2.x * w0.x + x2.y * w1.x + x2.z * w2.x + x2.w * w3.x;
            a2.y += x2.x * w0.y + x2.y * w1.y + x2.z * w2.y + x2.w * w3.y;
            a2.z += x2.x * w0.z + x2.y * w1.z + x2.z * w2.z + x2.w * w3.z;
            a2.w += x2.x * w0.w + x2.y * w1.w + x2.z * w2.w + x2.w * w3.w;

            a3.x += x3.x * w0.x + x3.y * w1.x + x3.z * w2.x + x3.w * w3.x;
            a3.y += x3.x * w0.y + x3.y * w1.y + x3.z * w2.y + x3.w * w3.y;
            a3.z += x3.x * w0.z + x3.y * w1.z + x3.z * w2.z + x3.w * w3.z;
            a3.w += x3.x * w0.w + x3.y * w1.w + x3.z * w2.w + x3.w * w3.w;
        }
    }

    int r0 = base + q;
    if (r0 < n) *(float4*)&out[(size_t)r0 * H + co] = a0;
    if (r0 + 16 < n) *(float4*)&out[(size_t)(r0 + 16) * H + co] = a1;
    if (r0 + 32 < n) *(float4*)&out[(size_t)(r0 + 32) * H + co] = a2;
    if (r0 + 48 < n) *(float4*)&out[(size_t)(r0 + 48) * H + co] = a3;
}

// ---------------- fused GCN aggregation + BN-stats ----------------
// Each wave handles TWO adjacent dst nodes (contiguous CSR ranges) -> 8
// independent gather chains in flight (R5/R6: more chains = more latency
// hidden; VGPR stays tiny). Epilogue: block-level LDS reduce of the fresh
// outputs + atomics into one of 64 stat slots (contention-spread; reduced by
// reduce_slots). Eliminates the standalone bn_stats 12.8 MB re-read.
__global__ void gcn_gather(const float* __restrict__ h, const int* __restrict__ row_start,
                           const int* __restrict__ csr_src, const float* __restrict__ dinv,
                           const float* __restrict__ bias, float* __restrict__ out,
                           float* __restrict__ slots, int n) {
    const int wv = threadIdx.x >> 6;
    const int c = threadIdx.x & 63;
    const int d0 = blockIdx.x * 8 + wv * 2;
    float vA = 0.f, vB = 0.f;
    if (d0 < n) {
        const int d1 = d0 + 1;  // n even -> d1 < n
        int jA = row_start[d0];
        const int jm = row_start[d1];
        const int je = row_start[d1 + 1];
        int jB = jm;
        float diA = dinv[d0], diB = dinv[d1];
        float bA = h[(size_t)d0 * H + c] * diA * diA + bias[c];
        float bB = h[(size_t)d1 * H + c] * diB * diB + bias[c];
        float a0 = 0.f, a1 = 0.f, a2 = 0.f, a3 = 0.f;
        float b0 = 0.f, b1 = 0.f, b2 = 0.f, b3 = 0.f;
        while (jA + 4 <= jm && jB + 4 <= je) {
            int sA0 = csr_src[jA + 0], sA1 = csr_src[jA + 1];
            int sA2 = csr_src[jA + 2], sA3 = csr_src[jA + 3];
            int sB0 = csr_src[jB + 0], sB1 = csr_src[jB + 1];
            int sB2 = csr_src[jB + 2], sB3 = csr_src[jB + 3];
            float wA0 = dinv[sA0], wA1 = dinv[sA1], wA2 = dinv[sA2], wA3 = dinv[sA3];
            float wB0 = dinv[sB0], wB1 = dinv[sB1], wB2 = dinv[sB2], wB3 = dinv[sB3];
            a0 += h[(size_t)sA0 * H + c] * wA0;
            a1 += h[(size_t)sA1 * H + c] * wA1;
            a2 += h[(size_t)sA2 * H + c] * wA2;
            a3 += h[(size_t)sA3 * H + c] * wA3;
            b0 += h[(size_t)sB0 * H + c] * wB0;
            b1 += h[(size_t)sB1 * H + c] * wB1;
            b2 += h[(size_t)sB2 * H + c] * wB2;
            b3 += h[(size_t)sB3 * H + c] * wB3;
            jA += 4;
            jB += 4;
        }
        for (; jA + 4 <= jm; jA += 4) {
            int s0 = csr_src[jA + 0], s1 = csr_src[jA + 1];
            int s2 = csr_src[jA + 2], s3 = csr_src[jA + 3];
            float w0 = dinv[s0], w1 = dinv[s1], w2 = dinv[s2], w3 = dinv[s3];
            a0 += h[(size_t)s0 * H + c] * w0;
            a1 += h[(size_t)s1 * H + c] * w1;
            a2 += h[(size_t)s2 * H + c] * w2;
            a3 += h[(size_t)s3 * H + c] * w3;
        }
        for (; jA < jm; ++jA) {
            int s = csr_src[jA];
            a0 += h[(size_t)s * H + c] * dinv[s];
        }
        for (; jB + 4 <= je; jB += 4) {
            int s0 = csr_src[jB + 0], s1 = csr_src[jB + 1];
            int s2 = csr_src[jB + 2], s3 = csr_src[jB + 3];
            float w0 = dinv[s0], w1 = dinv[s1], w2 = dinv[s2], w3 = dinv[s3];
            b0 += h[(size_t)s0 * H + c] * w0;
            b1 += h[(size_t)s1 * H + c] * w1;
            b2 += h[(size_t)s2 * H + c] * w2;
            b3 += h[(size_t)s3 * H + c] * w3;
        }
        for (; jB < je; ++jB) {
            int s = csr_src[jB];
            b0 += h[(size_t)s * H + c] * dinv[s];
        }
        vA = bA + diA * ((a0 + a1) + (a2 + a3));
        vB = bB + diB * ((b0 + b1) + (b2 + b3));
        out[(size_t)d0 * H + c] = vA;
        out[(size_t)d1 * H + c] = vB;
    }
    // fused BN stats into 64-way-spread slots
    __shared__ float ls[256], lq[256];
    ls[threadIdx.x] = vA + vB;
    lq[threadIdx.x] = vA * vA + vB * vB;
    __syncthreads();
    if (wv == 0) {
        float s = ls[c] + ls[c + 64] + ls[c + 128] + ls[c + 192];
        float q = lq[c] + lq[c + 64] + lq[c + 128] + lq[c + 192];
        float* slot = slots + (blockIdx.x & 63) * 128;
        atomicAdd(&slot[c], s);
        atomicAdd(&slot[64 + c], q);
    }
}

// ---------------- fold 64 stat slots into st[0..127] ----------------
__global__ void reduce_slots(const float* __restrict__ slots, float* __restrict__ st) {
    int c = threadIdx.x;  // 0..127
    float s0 = 0.f, s1 = 0.f, s2 = 0.f, s3 = 0.f;
    for (int k = 0; k < 64; k += 4) {
        s0 += slots[(k + 0) * 128 + c];
        s1 += slots[(k + 1) * 128 + c];
        s2 += slots[(k + 2) * 128 + c];
        s3 += slots[(k + 3) * 128 + c];
    }
    st[c] = (s0 + s1) + (s2 + s3);
}

// ---------------- global mean pool (fuses last BN finalize+apply+ReLU) ----------------
#define PROWS 16
__global__ void pool_seg(const float* __restrict__ h, const float* __restrict__ st,
                         const float* __restrict__ gamma, const float* __restrict__ beta,
                         const int* __restrict__ batch, float* __restrict__ pool,
                         float* __restrict__ cnt, int n) {
    int wave = blockIdx.x * 4 + (threadIdx.x >> 6);
    int c = threadIdx.x & 63;
    int r0 = wave * PROWS;
    if (r0 >= n) return;
    int r1 = min(r0 + PROWS, n);
    float mean = st[c] * INV_N;
    float var = st[64 + c] * INV_N - mean * mean;
    float sc = gamma[c] * rsqrtf(var + BN_EPS);
    float sh = beta[c] - mean * sc;
    int cur = batch[r0];
    float acc = 0.f;
    int nlocal = 0;
    for (int r = r0; r < r1; ++r) {
        int g = batch[r];
        if (g != cur) {
            atomicAdd(&pool[cur * H + c], acc);
            if (c == 0) atomicAdd(&cnt[cur], (float)nlocal);
            cur = g;
            acc = 0.f;
            nlocal = 0;
        }
        acc += fmaxf(h[(size_t)r * H + c] * sc + sh, 0.f);
        ++nlocal;
    }
    atomicAdd(&pool[cur * H + c], acc);
    if (c == 0) atomicAdd(&cnt[cur], (float)nlocal);
}

// ---------------- final MLP: lane = (graph, j) pair; shuffle-reduce over j --------------
__global__ void final_mlp(const float* __restrict__ pool, const float* __restrict__ cnt,
                          const float* __restrict__ l1w, const float* __restrict__ l1b,
                          const float* __restrict__ l2w, const float* __restrict__ l2b,
                          float* __restrict__ out) {
    int tid = blockIdx.x * 256 + threadIdx.x;
    int g = tid >> 5;
    int j = tid & 31;
    if (g >= NG) return;
    float inv = 1.0f / fmaxf(cnt[g], 1.0f);
    float s = l1b[j];
    for (int k = 0; k < H; ++k) s += pool[g * H + k] * inv * l1w[j * H + k];
    float v = fmaxf(s, 0.0f) * l2w[j];
    for (int off = 16; off > 0; off >>= 1) v += __shfl_down(v, off, 32);
    if (j == 0) out[g] = v + l2b[0];
}

extern "C" void kernel_launch(void* const* d_in, const int* in_sizes, int n_in,
                              void* d_out, int out_size, void* d_ws, size_t ws_size,
                              hipStream_t stream) {
    const float* x = (const float*)d_in[0];
    const int* ei = (const int*)d_in[1];
    const int* batch = (const int*)d_in[2];
    const float* W[3] = {(const float*)d_in[3], (const float*)d_in[7], (const float*)d_in[11]};
    const float* b[3] = {(const float*)d_in[4], (const float*)d_in[8], (const float*)d_in[12]};
    const float* g[3] = {(const float*)d_in[5], (const float*)d_in[9], (const float*)d_in[13]};
    const float* be[3] = {(const float*)d_in[6], (const float*)d_in[10], (const float*)d_in[14]};
    const float* l1w = (const float*)d_in[15];
    const float* l1b = (const float*)d_in[16];
    const float* l2w = (const float*)d_in[17];
    const float* l2b = (const float*)d_in[18];
    float* out = (float*)d_out;

    const int* src = ei;
    const int* dst = ei + NE;

    // ---- workspace layout (4-byte units) ----
    char* wsb = (char*)d_ws;
    size_t off = 0;
    auto alloc = [&](size_t elems) {
        void* p = wsb + off;
        off += elems * 4;
        return p;
    };
    float* dinv = (float*)alloc(50048);
    float* bufA = (float*)alloc((size_t)NN * H);
    float* bufB = (float*)alloc((size_t)NN * H);
    float* slots[3] = {(float*)alloc(64 * 128), (float*)alloc(64 * 128), (float*)alloc(64 * 128)};
    float* st[3] = {(float*)alloc(128), (float*)alloc(128), (float*)alloc(128)};
    float* pool = (float*)alloc(NG * H);
    float* cnt = (float*)alloc(64);
    float* Wt[3] = {(float*)alloc(FIN * 64), (float*)alloc(H * 64), (float*)alloc(H * 64)};
    int* deg = (int*)alloc(50048);
    int* row_start = (int*)alloc(50112);   // NN+1
    int* aux = (int*)alloc(256);
    int* bb = (int*)alloc(256);            // bucket bases (NBKT+1)
    int* bcur = (int*)alloc(256);          // bucket cursors
    unsigned int* staged = (unsigned int*)alloc(NE);
    int* csr_src = (int*)alloc(NE);

    // ---- build dinv + binned CSR (by dst) + transposed weights ----
    hipMemsetAsync(deg, 0, NN * sizeof(int), stream);
    deg_count<<<(NE + 255) / 256, 256, 0, stream>>>(dst, deg, NE);
    setup_misc<<<NB_SCAN, 256, 0, stream>>>(deg, dinv, W[0], W[1], W[2], Wt[0], Wt[1], Wt[2],
                                            slots[0], slots[1], slots[2], pool, NN);
    scan_block<<<NB_SCAN, 256, 0, stream>>>(deg, row_start, aux, NN);
    scan_aux<<<1, 256, 0, stream>>>(aux, NB_SCAN);
    scan_fixup<<<NB_SCAN, 256, 0, stream>>>(row_start, aux, bb, bcur, NN, NE);
    bin_edges<<<256, 256, 0, stream>>>(src, dst, bcur, staged, NE);
    csr_build<<<NBKT, 256, 0, stream>>>(staged, row_start, bb, csr_src, NN);

    const int grid_mm = (NN + 63) / 64;       // 782
    const int grid_gather = (NN + 7) / 8;     // 6250

    // ---- 3 GCN layers (BN of layer L-1 fused into layer L's X staging;
    //      BN stats of layer L fused into layer L's gather epilogue) ----
    for (int L = 0; L < 3; ++L) {
        if (L == 0)
            matmul_tile<FIN><<<grid_mm, 256, 0, stream>>>(x, Wt[0], nullptr, nullptr, nullptr,
                                                          bufA, NN);
        else
            matmul_tile<H><<<grid_mm, 256, 0, stream>>>(bufB, Wt[L], st[L - 1], g[L - 1],
                                                        be[L - 1], bufA, NN);
        gcn_gather<<<grid_gather, 256, 0, stream>>>(bufA, row_start, csr_src, dinv, b[L], bufB,
                                                    slots[L], NN);
        reduce_slots<<<1, 128, 0, stream>>>(slots[L], st[L]);
    }

    // ---- global mean pool (fused BN of layer 2) + MLP head ----
    const int pool_waves = (NN + PROWS - 1) / PROWS;  // 3125
    pool_seg<<<(pool_waves + 3) / 4, 256, 0, stream>>>(bufB, st[2], g[2], be[2], batch, pool,
                                                       cnt, NN);
    final_mlp<<<8, 256, 0, stream>>>(pool, cnt, l1w, l1b, l2w, l2b, out);
}

// Round 14
// 344.673 us; speedup vs baseline: 1.3546x; 1.0959x over previous
//
#include <hip/hip_runtime.h>

#define NN 50000
#define NE 800000
#define FIN 128
#define H 64
#define NG 64
#define BN_EPS 1e-5f
#define INV_N (1.0f / 50000.0f)
#define NBKT 196  // dst buckets of 256 nodes

// ---------------- setup: zero slots/pool/bucket counters, transpose all W ----------------
__global__ void setup_misc(const float* __restrict__ W0, const float* __restrict__ W1,
                           const float* __restrict__ W2, float* __restrict__ Wt0,
                           float* __restrict__ Wt1, float* __restrict__ Wt2,
                           float* __restrict__ sl0, float* __restrict__ sl1,
                           float* __restrict__ sl2, float* __restrict__ poolcnt,
                           int* __restrict__ bktcnt) {
    int i = blockIdx.x * 256 + threadIdx.x;
    if (i < 64 * 128) { sl0[i] = 0.f; sl1[i] = 0.f; sl2[i] = 0.f; }
    if (i < NG * H + NG) poolcnt[i] = 0.f;
    if (i < NBKT) bktcnt[i] = 0;
    if (i < FIN * 64) {
        int k = i >> 6, o = i & 63;
        Wt0[i] = W0[o * FIN + k];
    }
    if (i < H * 64) {
        int k = i >> 6, o = i & 63;
        Wt1[i] = W1[o * H + k];
        Wt2[i] = W2[o * H + k];
    }
}

// ---------------- bucket histogram (196 buckets of 256 dst nodes) ----------------
// R13->R14: replaces per-node deg_count (800k random global atomics) + 3-kernel
// 50k scan. Per-node degree/row_start now come from csr_build's in-LDS scan.
__global__ void bucket_hist(const int* __restrict__ dst, int* __restrict__ bktcnt, int E) {
    __shared__ int cnt[NBKT];
    const int chunk = (E + gridDim.x - 1) / gridDim.x;
    const int e0 = blockIdx.x * chunk;
    const int e1 = min(e0 + chunk, E);
    for (int i = threadIdx.x; i < NBKT; i += 256) cnt[i] = 0;
    __syncthreads();
    for (int e = e0 + threadIdx.x; e < e1; e += 256) atomicAdd(&cnt[dst[e] >> 8], 1);
    __syncthreads();
    for (int i = threadIdx.x; i < NBKT; i += 256)
        if (cnt[i]) atomicAdd(&bktcnt[i], cnt[i]);
}

// ---------------- exclusive scan over 196 bucket counts (1 block) ----------------
__global__ void bucket_scan(const int* __restrict__ bktcnt, int* __restrict__ bb,
                            int* __restrict__ bcur, int E) {
    __shared__ int s[256];
    int v = (threadIdx.x < NBKT) ? bktcnt[threadIdx.x] : 0;
    s[threadIdx.x] = v;
    __syncthreads();
    for (int off = 1; off < 256; off <<= 1) {
        int t = (threadIdx.x >= off) ? s[threadIdx.x - off] : 0;
        __syncthreads();
        s[threadIdx.x] += t;
        __syncthreads();
    }
    if (threadIdx.x < NBKT) {
        int base = s[threadIdx.x] - v;
        bb[threadIdx.x] = base;
        bcur[threadIdx.x] = base;
    }
    if (threadIdx.x == 0) bb[NBKT] = E;
}

// ---------------- stage edges bucket-contiguous (see R11 post-mortem) ----------------
// Random 4B scatters write back a full 64B line each (R10/R11: 50-52 MB for a
// 3.2 MB payload; atomicExch did NOT help). Staged bucket-major writes are
// line-dense; csr_build's random writes then span only ~16 KB per bucket.
__global__ void bin_edges(const int* __restrict__ src, const int* __restrict__ dst,
                          int* __restrict__ bcur, unsigned int* __restrict__ staged, int E) {
    __shared__ int cnt[NBKT];
    __shared__ int offs[NBKT];
    const int chunk = (E + gridDim.x - 1) / gridDim.x;
    const int e0 = blockIdx.x * chunk;
    const int e1 = min(e0 + chunk, E);
    for (int i = threadIdx.x; i < NBKT; i += 256) cnt[i] = 0;
    __syncthreads();
    for (int e = e0 + threadIdx.x; e < e1; e += 256) atomicAdd(&cnt[dst[e] >> 8], 1);
    __syncthreads();
    for (int i = threadIdx.x; i < NBKT; i += 256) {
        int c = cnt[i];
        offs[i] = c ? atomicAdd(&bcur[i], c) : 0;
        cnt[i] = 0;
    }
    __syncthreads();
    for (int e = e0 + threadIdx.x; e < e1; e += 256) {
        int d = dst[e];
        int bkt = d >> 8;
        int idx = atomicAdd(&cnt[bkt], 1);
        // src < 50000 fits in 16 bits; dst low byte in bits 16..23
        staged[offs[bkt] + idx] = (unsigned int)src[e] | ((unsigned int)(d & 255) << 16);
    }
}

// ---------------- per-bucket: node counts -> row_start/dinv + CSR scatter ----------------
__global__ void csr_build(const unsigned int* __restrict__ staged, const int* __restrict__ bb,
                          int* __restrict__ row_start, float* __restrict__ dinv,
                          int* __restrict__ csr_src, int n, int E) {
    __shared__ int cnt[256];
    __shared__ int loc[256];
    __shared__ int cur[256];
    const int b = blockIdx.x;
    cnt[threadIdx.x] = 0;
    __syncthreads();
    const int e0 = bb[b], e1 = bb[b + 1];
    for (int e = e0 + threadIdx.x; e < e1; e += 256)
        atomicAdd(&cnt[(staged[e] >> 16) & 255], 1);
    __syncthreads();
    int v = cnt[threadIdx.x];
    loc[threadIdx.x] = v;
    __syncthreads();
    for (int off = 1; off < 256; off <<= 1) {
        int t = (threadIdx.x >= off) ? loc[threadIdx.x - off] : 0;
        __syncthreads();
        loc[threadIdx.x] += t;
        __syncthreads();
    }
    const int start = e0 + loc[threadIdx.x] - v;  // exclusive
    const int node = b * 256 + threadIdx.x;
    if (node < n) {
        row_start[node] = start;
        dinv[node] = rsqrtf((float)v + 1.0f);
    }
    if (node == n) row_start[n] = E;
    cur[threadIdx.x] = start;
    __syncthreads();
    for (int e = e0 + threadIdx.x; e < e1; e += 256) {
        unsigned int u = staged[e];
        int j = atomicAdd(&cur[(u >> 16) & 255], 1);
        csr_src[j] = (int)(u & 0xFFFFu);
    }
}

// ---------------- tiled matmul: out = relu_bn(x) @ W^T ----------------
template <int K>
__global__ __launch_bounds__(256, 4) void matmul_tile(const float* __restrict__ x,
                                                      const float* __restrict__ Wtg,
                                                      const float* __restrict__ st,
                                                      const float* __restrict__ gamma,
                                                      const float* __restrict__ beta,
                                                      float* __restrict__ out, int n) {
    __shared__ float Xs[64 * 68];
    __shared__ float Ws[64 * 64];
    const int base = blockIdx.x * 64;
    const int q = threadIdx.x >> 4;         // 0..15
    const int co = (threadIdx.x & 15) * 4;  // 0..60

    float4 a0 = make_float4(0.f, 0.f, 0.f, 0.f);
    float4 a1 = a0, a2 = a0, a3 = a0;

    for (int kc = 0; kc < K; kc += 64) {
        if (kc) __syncthreads();
        for (int i = threadIdx.x; i < 64 * 64; i += 256) Ws[i] = Wtg[kc * 64 + i];
        {
            const int kq = (threadIdx.x & 15) * 4;
            float4 sc = make_float4(1.f, 1.f, 1.f, 1.f);
            float4 sh = make_float4(0.f, 0.f, 0.f, 0.f);
            if (st) {
                int kk = kc + kq;
                float4 s = *(const float4*)&st[kk];
                float4 ss = *(const float4*)&st[64 + kk];
                float4 gm = *(const float4*)&gamma[kk];
                float4 bt = *(const float4*)&beta[kk];
                float mx = s.x * INV_N, my = s.y * INV_N, mz = s.z * INV_N, mw = s.w * INV_N;
                sc.x = gm.x * rsqrtf(ss.x * INV_N - mx * mx + BN_EPS);
                sc.y = gm.y * rsqrtf(ss.y * INV_N - my * my + BN_EPS);
                sc.z = gm.z * rsqrtf(ss.z * INV_N - mz * mz + BN_EPS);
                sc.w = gm.w * rsqrtf(ss.w * INV_N - mw * mw + BN_EPS);
                sh.x = bt.x - mx * sc.x;
                sh.y = bt.y - my * sc.y;
                sh.z = bt.z - mz * sc.z;
                sh.w = bt.w - mw * sc.w;
            }
            for (int j = 0; j < 4; ++j) {
                int r = (threadIdx.x >> 4) + j * 16;
                int row = base + r;
                float4 v = make_float4(0.f, 0.f, 0.f, 0.f);
                if (row < n) v = *(const float4*)&x[(size_t)row * K + kc + kq];
                if (st) {
                    v.x = fmaxf(v.x * sc.x + sh.x, 0.f);
                    v.y = fmaxf(v.y * sc.y + sh.y, 0.f);
                    v.z = fmaxf(v.z * sc.z + sh.z, 0.f);
                    v.w = fmaxf(v.w * sc.w + sh.w, 0.f);
                }
                *(float4*)&Xs[r * 68 + kq] = v;
            }
        }
        __syncthreads();

#pragma unroll 2
        for (int k = 0; k < 64; k += 4) {
            float4 x0 = *(const float4*)&Xs[(q + 0) * 68 + k];
            float4 x1 = *(const float4*)&Xs[(q + 16) * 68 + k];
            float4 x2 = *(const float4*)&Xs[(q + 32) * 68 + k];
            float4 x3 = *(const float4*)&Xs[(q + 48) * 68 + k];
            float4 w0 = *(const float4*)&Ws[(k + 0) * 64 + co];
            float4 w1 = *(const float4*)&Ws[(k + 1) * 64 + co];
            float4 w2 = *(const float4*)&Ws[(k + 2) * 64 + co];
            float4 w3 = *(const float4*)&Ws[(k + 3) * 64 + co];

            a0.x += x0.x * w0.x + x0.y * w1.x + x0.z * w2.x + x0.w * w3.x;
            a0.y += x0.x * w0.y + x0.y * w1.y + x0.z * w2.y + x0.w * w3.y;
            a0.z += x0.x * w0.z + x0.y * w1.z + x0.z * w2.z + x0.w * w3.z;
            a0.w += x0.x * w0.w + x0.y * w1.w + x0.z * w2.w + x0.w * w3.w;

            a1.x += x1.x * w0.x + x1.y * w1.x + x1.z * w2.x + x1.w * w3.x;
            a1.y += x1.x * w0.y + x1.y * w1.y + x1.z * w2.y + x1.w * w3.y;
            a1.z += x1.x * w0.z + x1.y * w1.z + x1.z * w2.z + x1.w * w3.z;
            a1.w += x1.x * w0.w + x1.y * w1.w + x1.z * w2.w + x1.w * w3.w;

            a2.x += x2.x * w0.x + x2.y * w1.x + x2.z * w2.x + x2.w * w3.x;
            a2.y += x2.x * w0.y + x2.y * w1.y + x2.z * w2.y + x2.w * w3.y;
            a2.z += x2.x * w0.z + x2.y * w1.z + x2.z * w2.z + x2.w * w3.z;
            a2.w += x2.x * w0.w + x2.y * w1.w + x2.z * w2.w + x2.w * w3.w;

            a3.x += x3.x * w0.x + x3.y * w1.x + x3.z * w2.x + x3.w * w3.x;
            a3.y += x3.x * w0.y + x3.y * w1.y + x3.z * w2.y + x3.w * w3.y;
            a3.z += x3.x * w0.z + x3.y * w1.z + x3.z * w2.z + x3.w * w3.z;
            a3.w += x3.x * w0.w + x3.y * w1.w + x3.z * w2.w + x3.w * w3.w;
        }
    }

    int r0 = base + q;
    if (r0 < n) *(float4*)&out[(size_t)r0 * H + co] = a0;
    if (r0 + 16 < n) *(float4*)&out[(size_t)(r0 + 16) * H + co] = a1;
    if (r0 + 32 < n) *(float4*)&out[(size_t)(r0 + 32) * H + co] = a2;
    if (r0 + 48 < n) *(float4*)&out[(size_t)(r0 + 48) * H + co] = a3;
}

// ---------------- fused GCN aggregation + BN-stats ----------------
// Two adjacent dst nodes per wave -> 8 independent gather chains in flight.
// Epilogue: LDS reduce + atomics into 64-way-spread stat slots.
__global__ void gcn_gather(const float* __restrict__ h, const int* __restrict__ row_start,
                           const int* __restrict__ csr_src, const float* __restrict__ dinv,
                           const float* __restrict__ bias, float* __restrict__ out,
                           float* __restrict__ slots, int n) {
    const int wv = threadIdx.x >> 6;
    const int c = threadIdx.x & 63;
    const int d0 = blockIdx.x * 8 + wv * 2;
    float vA = 0.f, vB = 0.f;
    if (d0 < n) {
        const int d1 = d0 + 1;  // n even -> d1 < n
        int jA = row_start[d0];
        const int jm = row_start[d1];
        const int je = row_start[d1 + 1];
        int jB = jm;
        float diA = dinv[d0], diB = dinv[d1];
        float bA = h[(size_t)d0 * H + c] * diA * diA + bias[c];
        float bB = h[(size_t)d1 * H + c] * diB * diB + bias[c];
        float a0 = 0.f, a1 = 0.f, a2 = 0.f, a3 = 0.f;
        float b0 = 0.f, b1 = 0.f, b2 = 0.f, b3 = 0.f;
        while (jA + 4 <= jm && jB + 4 <= je) {
            int sA0 = csr_src[jA + 0], sA1 = csr_src[jA + 1];
            int sA2 = csr_src[jA + 2], sA3 = csr_src[jA + 3];
            int sB0 = csr_src[jB + 0], sB1 = csr_src[jB + 1];
            int sB2 = csr_src[jB + 2], sB3 = csr_src[jB + 3];
            float wA0 = dinv[sA0], wA1 = dinv[sA1], wA2 = dinv[sA2], wA3 = dinv[sA3];
            float wB0 = dinv[sB0], wB1 = dinv[sB1], wB2 = dinv[sB2], wB3 = dinv[sB3];
            a0 += h[(size_t)sA0 * H + c] * wA0;
            a1 += h[(size_t)sA1 * H + c] * wA1;
            a2 += h[(size_t)sA2 * H + c] * wA2;
            a3 += h[(size_t)sA3 * H + c] * wA3;
            b0 += h[(size_t)sB0 * H + c] * wB0;
            b1 += h[(size_t)sB1 * H + c] * wB1;
            b2 += h[(size_t)sB2 * H + c] * wB2;
            b3 += h[(size_t)sB3 * H + c] * wB3;
            jA += 4;
            jB += 4;
        }
        for (; jA + 4 <= jm; jA += 4) {
            int s0 = csr_src[jA + 0], s1 = csr_src[jA + 1];
            int s2 = csr_src[jA + 2], s3 = csr_src[jA + 3];
            float w0 = dinv[s0], w1 = dinv[s1], w2 = dinv[s2], w3 = dinv[s3];
            a0 += h[(size_t)s0 * H + c] * w0;
            a1 += h[(size_t)s1 * H + c] * w1;
            a2 += h[(size_t)s2 * H + c] * w2;
            a3 += h[(size_t)s3 * H + c] * w3;
        }
        for (; jA < jm; ++jA) {
            int s = csr_src[jA];
            a0 += h[(size_t)s * H + c] * dinv[s];
        }
        for (; jB + 4 <= je; jB += 4) {
            int s0 = csr_src[jB + 0], s1 = csr_src[jB + 1];
            int s2 = csr_src[jB + 2], s3 = csr_src[jB + 3];
            float w0 = dinv[s0], w1 = dinv[s1], w2 = dinv[s2], w3 = dinv[s3];
            b0 += h[(size_t)s0 * H + c] * w0;
            b1 += h[(size_t)s1 * H + c] * w1;
            b2 += h[(size_t)s2 * H + c] * w2;
            b3 += h[(size_t)s3 * H + c] * w3;
        }
        for (; jB < je; ++jB) {
            int s = csr_src[jB];
            b0 += h[(size_t)s * H + c] * dinv[s];
        }
        vA = bA + diA * ((a0 + a1) + (a2 + a3));
        vB = bB + diB * ((b0 + b1) + (b2 + b3));
        out[(size_t)d0 * H + c] = vA;
        out[(size_t)d1 * H + c] = vB;
    }
    __shared__ float ls[256], lq[256];
    ls[threadIdx.x] = vA + vB;
    lq[threadIdx.x] = vA * vA + vB * vB;
    __syncthreads();
    if (wv == 0) {
        float s = ls[c] + ls[c + 64] + ls[c + 128] + ls[c + 192];
        float q = lq[c] + lq[c + 64] + lq[c + 128] + lq[c + 192];
        float* slot = slots + (blockIdx.x & 63) * 128;
        atomicAdd(&slot[c], s);
        atomicAdd(&slot[64 + c], q);
    }
}

// ---------------- fold 64 stat slots into st[0..127] ----------------
__global__ void reduce_slots(const float* __restrict__ slots, float* __restrict__ st) {
    int c = threadIdx.x;  // 0..127
    float s0 = 0.f, s1 = 0.f, s2 = 0.f, s3 = 0.f;
    for (int k = 0; k < 64; k += 4) {
        s0 += slots[(k + 0) * 128 + c];
        s1 += slots[(k + 1) * 128 + c];
        s2 += slots[(k + 2) * 128 + c];
        s3 += slots[(k + 3) * 128 + c];
    }
    st[c] = (s0 + s1) + (s2 + s3);
}

// ---------------- global mean pool (fuses last BN finalize+apply+ReLU) ----------------
#define PROWS 16
__global__ void pool_seg(const float* __restrict__ h, const float* __restrict__ st,
                         const float* __restrict__ gamma, const float* __restrict__ beta,
                         const int* __restrict__ batch, float* __restrict__ pool,
                         float* __restrict__ cnt, int n) {
    int wave = blockIdx.x * 4 + (threadIdx.x >> 6);
    int c = threadIdx.x & 63;
    int r0 = wave * PROWS;
    if (r0 >= n) return;
    int r1 = min(r0 + PROWS, n);
    float mean = st[c] * INV_N;
    float var = st[64 + c] * INV_N - mean * mean;
    float sc = gamma[c] * rsqrtf(var + BN_EPS);
    float sh = beta[c] - mean * sc;
    int cur = batch[r0];
    float acc = 0.f;
    int nlocal = 0;
    for (int r = r0; r < r1; ++r) {
        int g = batch[r];
        if (g != cur) {
            atomicAdd(&pool[cur * H + c], acc);
            if (c == 0) atomicAdd(&cnt[cur], (float)nlocal);
            cur = g;
            acc = 0.f;
            nlocal = 0;
        }
        acc += fmaxf(h[(size_t)r * H + c] * sc + sh, 0.f);
        ++nlocal;
    }
    atomicAdd(&pool[cur * H + c], acc);
    if (c == 0) atomicAdd(&cnt[cur], (float)nlocal);
}

// ---------------- final MLP: lane = (graph, j) pair; shuffle-reduce over j --------------
__global__ void final_mlp(const float* __restrict__ pool, const float* __restrict__ cnt,
                          const float* __restrict__ l1w, const float* __restrict__ l1b,
                          const float* __restrict__ l2w, const float* __restrict__ l2b,
                          float* __restrict__ out) {
    int tid = blockIdx.x * 256 + threadIdx.x;
    int g = tid >> 5;
    int j = tid & 31;
    if (g >= NG) return;
    float inv = 1.0f / fmaxf(cnt[g], 1.0f);
    float s = l1b[j];
    for (int k = 0; k < H; ++k) s += pool[g * H + k] * inv * l1w[j * H + k];
    float v = fmaxf(s, 0.0f) * l2w[j];
    for (int off = 16; off > 0; off >>= 1) v += __shfl_down(v, off, 32);
    if (j == 0) out[g] = v + l2b[0];
}

extern "C" void kernel_launch(void* const* d_in, const int* in_sizes, int n_in,
                              void* d_out, int out_size, void* d_ws, size_t ws_size,
                              hipStream_t stream) {
    const float* x = (const float*)d_in[0];
    const int* ei = (const int*)d_in[1];
    const int* batch = (const int*)d_in[2];
    const float* W[3] = {(const float*)d_in[3], (const float*)d_in[7], (const float*)d_in[11]};
    const float* b[3] = {(const float*)d_in[4], (const float*)d_in[8], (const float*)d_in[12]};
    const float* g[3] = {(const float*)d_in[5], (const float*)d_in[9], (const float*)d_in[13]};
    const float* be[3] = {(const float*)d_in[6], (const float*)d_in[10], (const float*)d_in[14]};
    const float* l1w = (const float*)d_in[15];
    const float* l1b = (const float*)d_in[16];
    const float* l2w = (const float*)d_in[17];
    const float* l2b = (const float*)d_in[18];
    float* out = (float*)d_out;

    const int* src = ei;
    const int* dst = ei + NE;

    // ---- workspace layout (4-byte units) ----
    char* wsb = (char*)d_ws;
    size_t off = 0;
    auto alloc = [&](size_t elems) {
        void* p = wsb + off;
        off += elems * 4;
        return p;
    };
    float* dinv = (float*)alloc(50048);
    float* bufA = (float*)alloc((size_t)NN * H);
    float* bufB = (float*)alloc((size_t)NN * H);
    float* slots[3] = {(float*)alloc(64 * 128), (float*)alloc(64 * 128), (float*)alloc(64 * 128)};
    float* st[3] = {(float*)alloc(128), (float*)alloc(128), (float*)alloc(128)};
    float* pool = (float*)alloc(NG * H);
    float* cnt = (float*)alloc(64);
    float* Wt[3] = {(float*)alloc(FIN * 64), (float*)alloc(H * 64), (float*)alloc(H * 64)};
    int* row_start = (int*)alloc(50112);   // NN+1
    int* bktcnt = (int*)alloc(256);        // NBKT
    int* bb = (int*)alloc(256);            // bucket bases (NBKT+1)
    int* bcur = (int*)alloc(256);          // bucket cursors
    unsigned int* staged = (unsigned int*)alloc(NE);
    int* csr_src = (int*)alloc(NE);

    // ---- setup + binned CSR build (no per-node deg pass, no 50k scan) ----
    setup_misc<<<32, 256, 0, stream>>>(W[0], W[1], W[2], Wt[0], Wt[1], Wt[2], slots[0], slots[1],
                                       slots[2], pool, bktcnt);
    bucket_hist<<<256, 256, 0, stream>>>(dst, bktcnt, NE);
    bucket_scan<<<1, 256, 0, stream>>>(bktcnt, bb, bcur, NE);
    bin_edges<<<256, 256, 0, stream>>>(src, dst, bcur, staged, NE);
    csr_build<<<NBKT, 256, 0, stream>>>(staged, bb, row_start, dinv, csr_src, NN, NE);

    const int grid_mm = (NN + 63) / 64;       // 782
    const int grid_gather = (NN + 7) / 8;     // 6250

    // ---- 3 GCN layers (BN of layer L-1 fused into layer L's X staging;
    //      BN stats of layer L fused into layer L's gather epilogue) ----
    for (int L = 0; L < 3; ++L) {
        if (L == 0)
            matmul_tile<FIN><<<grid_mm, 256, 0, stream>>>(x, Wt[0], nullptr, nullptr, nullptr,
                                                          bufA, NN);
        else
            matmul_tile<H><<<grid_mm, 256, 0, stream>>>(bufB, Wt[L], st[L - 1], g[L - 1],
                                                        be[L - 1], bufA, NN);
        gcn_gather<<<grid_gather, 256, 0, stream>>>(bufA, row_start, csr_src, dinv, b[L], bufB,
                                                    slots[L], NN);
        reduce_slots<<<1, 128, 0, stream>>>(slots[L], st[L]);
    }

    // ---- global mean pool (fused BN of layer 2) + MLP head ----
    const int pool_waves = (NN + PROWS - 1) / PROWS;  // 3125
    pool_seg<<<(pool_waves + 3) / 4, 256, 0, stream>>>(bufB, st[2], g[2], be[2], batch, pool,
                                                       cnt, NN);
    final_mlp<<<8, 256, 0, stream>>>(pool, cnt, l1w, l1b, l2w, l2b, out);
}